// Round 2
// baseline (117.801 us; speedup 1.0000x reference)
//
#include <hip/hip_runtime.h>

#define BATCH 64
#define NN 256
// Scaled DP domain: V' = V * CSC, CSC = (1/gamma)*log2(e), gamma = 0.01.
#define CSC   144.26950408889634f
#define RCSC  0.0069314718055994531f   // 1/CSC = gamma*ln(2)
#define BIGS  1.4426950408889634e10f   // 1e8 * CSC (scaled boundary)

// TWO batches per block (512 threads, 8 waves): waves 0-3 = batch 2*blk,
// waves 4-7 = batch 2*blk+1. Each wave runs the identical per-wave program
// as the 1-batch version (4 waves per batch, 1 DP row per lane: within a
// batch, wave w / lane l owns row i = 64w+l+1). The two co-resident waves
// per SIMD interleave so dependence/transcendental stalls of one DP are
// filled by the other's issue (latency-bound -> TLP fill).
//
// Skewed wavefront: at global iter n, wave w computes diag k = n + 2 - 8w.
// Intra-wave row handoff: DPP wave_shr1 (lane 0 receives the cross-wave
// boundary value via the DPP `old` operand). Cross-wave handoff: lane 63
// publishes (V',tangent) to a 16-slot LDS ring; consumer (wave w+1) needs the
// value 9 iters after it was written, reads it with a 2-iter prefetch, and a
// barrier every 4 iters orders write->read (write t-9 vs read-issue t-2 always
// straddles >=1 barrier; 16 slots make overwrite races impossible). Barriers
// now sync 8 waves; both halves follow the identical schedule so the ring
// safety argument is unchanged per half.
// o operand also flows down-lane by DPP; lane 0 injects o[n - 72w] each iter
// from broadcast-prefetched float4s. BIG self-propagation (round-4-validated)
// makes all skew startup/tail cells harmless; ring pre-init = (BIGS, 0).
// Temporal term = JVP tangent of V[N,N] with seed omega[i,j] = (i-j)^2.

__device__ __forceinline__ float shr1(float x, float old) {
    return __int_as_float(__builtin_amdgcn_update_dpp(
        __float_as_int(old), __float_as_int(x), 0x138, 0xF, 0xF, false));
}

#define ITER(J, OINJ) {                                              \
    float sA = shr1(A, rdcA);                                        \
    float sU = shr1(U, rdcU);                                        \
    oc = shr1(oc, OINJ);                                             \
    rdcA = rdnA; rdcU = rdnU;                                        \
    float2 rr = ringr[((J) + 9) & 15];   /* for iter n+2 */          \
    rdnA = rr.x; rdnU = rr.y;                                        \
    float m  = fminf(fminf(A, psA), sA);                             \
    float el = __builtin_amdgcn_exp2f(m - A);                        \
    float ed = __builtin_amdgcn_exp2f(m - psA);                      \
    float eu = __builtin_amdgcn_exp2f(m - sA);                       \
    float s  = el + ed + eu;                                         \
    float x  = T - oc;                                               \
    float nv = fmaf(CSC * x, x, m - __builtin_amdgcn_logf(s));       \
    float num = fmaf(el, U, fmaf(ed, psU, eu * sU));                 \
    float nt  = fmaf(num, __builtin_amdgcn_rcpf(s), dr * dr);        \
    if (l63) ringw[(J)] = make_float2(nv, nt);                       \
    psA = sA; psU = sU; A = nv; U = nt; dr -= 1.0f;                  \
}

__global__ __launch_bounds__(512) void dilate_fused(
    const float* __restrict__ y_pred,
    const float* __restrict__ y_true,
    float* __restrict__ out)
{
    const int tid = threadIdx.x;          // 0..511
    const int h   = tid >> 8;             // batch half within block
    const int q   = tid & 255;            // within-batch thread id
    const int b   = blockIdx.x * 2 + h;   // batch index
    const int w   = q >> 6;               // wave within batch (0..3)
    const int l   = tid & 63;
    const bool l63 = (l == 63);

    __shared__ float  o_lds[2][1088];   // per half: zeros | o at [512,768) | zeros
    __shared__ float2 ring[2][5][16];   // per half: [row w (4 = const BIGS row)][slot]

    float* oh = o_lds[h];
    const float4 z4 = make_float4(0.f, 0.f, 0.f, 0.f);
    if (q < 128) ((float4*)oh)[q] = z4;                              // [0,512)
    if (q >= 128 && q < 208) ((float4*)oh)[q + 64] = z4;             // [768,1088)
    if (q < 64) ((float4*)(oh + 512))[q] =
        ((const float4*)(y_pred + b * NN))[q];                       // o
    if (q < 80) ((float2*)ring[h])[q] = make_float2(BIGS, 0.f);      // all slots

    const float T = y_true[b * NN + q];                              // row i = q+1
    __syncthreads();

    float A = BIGS, U = 0.f;
    float psA = (q == 0) ? 0.f : BIGS;                               // V[0,0] corner
    float psU = 0.f;
    float oc = 0.f;
    float dr = (float)(2 * q + 8 * w);                               // (i - j) at n=0
    float rdcA = BIGS, rdcU = 0.f, rdnA = BIGS, rdnU = 0.f;

    float2* ringw = ring[h][w];
    const float2* ringr = ring[h][(w == 0) ? 4 : (w - 1)];
    const float4* o4 = ((const float4*)oh) + (128 - 18 * w);

    float4 fA = o4[0], fB = o4[1], fC = o4[2], fD = o4[3]; o4 += 4;

    #pragma unroll 1
    for (int blk = 0; blk < 33; ++blk) {                             // n = 0..527
        float4 gA = o4[0], gB = o4[1], gC = o4[2], gD = o4[3]; o4 += 4;
        ITER(0,  fA.x) ITER(1,  fA.y) ITER(2,  fA.z) ITER(3,  fA.w)
        __syncthreads();
        ITER(4,  fB.x) ITER(5,  fB.y) ITER(6,  fB.z) ITER(7,  fB.w)
        __syncthreads();
        ITER(8,  fC.x) ITER(9,  fC.y) ITER(10, fC.z) ITER(11, fC.w)
        __syncthreads();
        ITER(12, fD.x) ITER(13, fD.y) ITER(14, fD.z) ITER(15, fD.w)
        __syncthreads();
        fA = gA; fB = gB; fC = gC; fD = gD;
    }
    // peel n = 528..534 (wave 3 reaches k = 512 at n = 534); no barriers needed:
    // peel writes are never consumed, peel reads target slots 9..15 (disjoint
    // from peel-written slots 0..6) and data written before the last barrier.
    ITER(0, fA.x) ITER(1, fA.y) ITER(2, fA.z) ITER(3, fA.w)
    ITER(4, fB.x) ITER(5, fB.y) ITER(6, fB.z)

    if (q == 255) {                         // per half: wave 3, lane 63 = (256,256)
        float loss = 0.5f * (A * RCSC) * (1.0f / BATCH)
                   + 0.5f * U * (1.0f / ((float)BATCH * (float)(NN * NN)));
        atomicAdd(out, loss);
    }
}

extern "C" void kernel_launch(void* const* d_in, const int* in_sizes, int n_in,
                              void* d_out, int out_size, void* d_ws, size_t ws_size,
                              hipStream_t stream)
{
    const float* y_pred = (const float*)d_in[0];   // [64,256,1] -> o (columns)
    const float* y_true = (const float*)d_in[1];   // [64,256,1] -> t (rows)
    hipMemsetAsync(d_out, 0, sizeof(float), stream);
    dilate_fused<<<BATCH / 2, 512, 0, stream>>>(y_pred, y_true, (float*)d_out);
}

// Round 3
// 114.852 us; speedup vs baseline: 1.0257x; 1.0257x over previous
//
#include <hip/hip_runtime.h>

#define BATCH 64
#define NN 256
// Scaled DP domain: V' = V * CSC, CSC = (1/gamma)*log2(e), gamma = 0.01.
#define CSC   144.26950408889634f
#define RCSC  0.0069314718055994531f   // 1/CSC = gamma*ln(2)
#define BIGS  1.4426950408889634e10f   // 1e8 * CSC (scaled boundary)

// ONE wave per batch, 4 rows per lane, ZERO barriers / ring / cross-wave sync.
// Lane l owns rows i = 4l+1..4l+4, all at the SAME column; at iter n lane l
// computes column c = n - l + 1 (skew 1 per lane, 256+63 = 319 iterations,
// the minimal diagonal count vs 535 in the 4-wave version).
// Dependencies:
//   row 1: up  = V(4l, c)   = lane l-1's A4 after iter n-1  -> DPP shr1
//          diag= V(4l, c-1) = lane l-1's A4 after iter n-2  -> pdA (prev sA)
//          lane 0: up/diag = BIGS constant (V(0,*) boundary; pdA init 0 = V(0,0))
//   row r>=2: up = new A_{r-1} (this iter), diag = old A_{r-1} (prev iter),
//          both in-register (rows of a lane share the column).
//   o flows down-lane by one DPP/iter; lane 0 injects o[n] from broadcast
//   float4 prefetch out of LDS (zero-padded past 256 for the tail).
// BIG self-propagation (validated in the 4-wave kernel) makes all startup/
// tail cells harmless: exp2(x - BIGS) == 0 exactly kills garbage paths.
// Temporal term = JVP tangent with seed omega(i,j) = (i-j)^2, identical
// per-cell formula as the passing kernel (bitwise-same cell math).

__device__ __forceinline__ float shr1(float x, float old) {
    return __int_as_float(__builtin_amdgcn_update_dpp(
        __float_as_int(old), __float_as_int(x), 0x138, 0xF, 0xF, false));
}

// One DP cell: (A,U) <- update from left (A,U), diag (dA,dU), up (uA,uU).
// t = row target value, drv = (i - j) for this cell, oc = o_j (shared/lane).
#define CELL(A, U, dA, dU, uA, uU, t, drv) {                         \
    float m  = fminf(fminf((A), (dA)), (uA));                        \
    float el = __builtin_amdgcn_exp2f(m - (A));                      \
    float ed = __builtin_amdgcn_exp2f(m - (dA));                     \
    float eu = __builtin_amdgcn_exp2f(m - (uA));                     \
    float s  = el + ed + eu;                                         \
    float x  = (t) - oc;                                             \
    float nv = fmaf(CSC * x, x, m - __builtin_amdgcn_logf(s));       \
    float num = fmaf(el, (U), fmaf(ed, (dU), eu * (uU)));            \
    float dv = (drv);                                                \
    float nt  = fmaf(num, __builtin_amdgcn_rcpf(s), dv * dv);        \
    (A) = nv; (U) = nt;                                              \
}

#define ITER(OINJ) {                                                 \
    float sA = shr1(A4, BIGS);          /* lane0: V(0,c) = BIG */    \
    float sU = shr1(U4, 0.f);                                        \
    oc = shr1(oc, OINJ);                /* lane0: o[n] */            \
    float oA1 = A1, oU1 = U1;                                        \
    CELL(A1, U1, pdA, pdU, sA, sU, T.x, drb)                         \
    pdA = sA; pdU = sU;                                              \
    float oA2 = A2, oU2 = U2;                                        \
    CELL(A2, U2, oA1, oU1, A1, U1, T.y, drb + 1.0f)                  \
    float oA3 = A3, oU3 = U3;                                        \
    CELL(A3, U3, oA2, oU2, A2, U2, T.z, drb + 2.0f)                  \
    CELL(A4, U4, oA3, oU3, A3, U3, T.w, drb + 3.0f)                  \
    drb -= 1.0f;                                                     \
}

__global__ __launch_bounds__(64) void dilate_fused(
    const float* __restrict__ y_pred,
    const float* __restrict__ y_true,
    float* __restrict__ out)
{
    const int b = blockIdx.x;
    const int l = threadIdx.x;            // 0..63, one wave

    __shared__ float o_lds[336];          // o[0..255] | zeros [256..335]

    ((float4*)o_lds)[l] = ((const float4*)(y_pred + b * NN))[l];
    if (l < 20) ((float4*)o_lds)[64 + l] = make_float4(0.f, 0.f, 0.f, 0.f);
    __syncthreads();                      // single-wave: compiles to waitcnt

    const float4 T = ((const float4*)(y_true + b * NN))[l];  // rows 4l+1..4l+4

    float A1 = BIGS, A2 = BIGS, A3 = BIGS, A4 = BIGS;
    float U1 = 0.f,  U2 = 0.f,  U3 = 0.f,  U4 = 0.f;
    float pdA = (l == 0) ? 0.f : BIGS;    // row-1 diag; lane0 n=0: V(0,0)=0
    float pdU = 0.f;
    float oc  = 0.f;
    float drb = (float)(5 * l);           // (i-j) of row 1 at n=0: 5l + 0

    const float4* o4 = (const float4*)o_lds;
    float4 fA = o4[0], fB = o4[1], fC = o4[2], fD = o4[3]; o4 += 4;

    #pragma unroll 1
    for (int blk = 0; blk < 19; ++blk) {              // n = 0..303
        float4 gA = o4[0], gB = o4[1], gC = o4[2], gD = o4[3]; o4 += 4;
        ITER(fA.x) ITER(fA.y) ITER(fA.z) ITER(fA.w)
        ITER(fB.x) ITER(fB.y) ITER(fB.z) ITER(fB.w)
        ITER(fC.x) ITER(fC.y) ITER(fC.z) ITER(fC.w)
        ITER(fD.x) ITER(fD.y) ITER(fD.z) ITER(fD.w)
        fA = gA; fB = gB; fC = gC; fD = gD;
    }
    // peel n = 304..318: lane 63 computes its final column c=256 at n=318.
    ITER(fA.x) ITER(fA.y) ITER(fA.z) ITER(fA.w)
    ITER(fB.x) ITER(fB.y) ITER(fB.z) ITER(fB.w)
    ITER(fC.x) ITER(fC.y) ITER(fC.z) ITER(fC.w)
    ITER(fD.x) ITER(fD.y) ITER(fD.z)

    if (l == 63) {                        // lane 63 row 4 = cell (256,256)
        float loss = 0.5f * (A4 * RCSC) * (1.0f / BATCH)
                   + 0.5f * U4 * (1.0f / ((float)BATCH * (float)(NN * NN)));
        atomicAdd(out, loss);
    }
}

extern "C" void kernel_launch(void* const* d_in, const int* in_sizes, int n_in,
                              void* d_out, int out_size, void* d_ws, size_t ws_size,
                              hipStream_t stream)
{
    const float* y_pred = (const float*)d_in[0];   // [64,256,1] -> o (columns)
    const float* y_true = (const float*)d_in[1];   // [64,256,1] -> t (rows)
    hipMemsetAsync(d_out, 0, sizeof(float), stream);
    dilate_fused<<<BATCH, 64, 0, stream>>>(y_pred, y_true, (float*)d_out);
}

// Round 7
// 113.018 us; speedup vs baseline: 1.0423x; 1.0162x over previous
//
#include <hip/hip_runtime.h>

#define BATCH 64
#define NN 256
// Scaled DP domain: V' = V * CSC, CSC = (1/gamma)*log2(e), gamma = 0.01.
#define CSC   144.26950408889634f
#define RCSC  0.0069314718055994531f   // 1/CSC = gamma*ln(2)
#define BIGS  1.4426950408889634e10f   // 1e8 * CSC (scaled boundary)

// R0 structure (4 waves per batch, 1 DP row per lane, skewed wavefront,
// 16-slot LDS ring, barrier every 4 iters) with SHIFT-DEFERRED softmin:
// V = a - log2(s). Weights: e_k = s_k * exp2(m - a_k) == exp2(m - V_k)
// (shift invariance), s' = sum e_k, tangent U' = num*rcp(s') + omega —
// recurrence identical to the proven 45.9us eager kernel. The deferral:
// a' = d' + m leaves "- log2(s)" off the V critical path (chain =
// DPP -> min3 -> fma, ~15 cyc vs ~40); the log is absorbed every 4 iters
// by STRIP: Aa -= log2(As); As = 1 (value-invariant; no-op on BIG cells).
//
// NaN-PROOFING (R4/R6 both NaN'd; algebra says impossible -> bound the
// channels by construction): (1) the single s-channel ingress `us` (all
// s values flow through this DPP: pds inherits it, ring values pass
// through it at lane 0) is clamped to [1, 65536] — exact identity for
// legit values (real-cell s <= ~6.6e3 incl. the 7-iter unstripped peel;
// wedge cells are exp2-killed regardless); (2) nt clamped to <= 1e30 at
// creation (legit U <= ~1.5e8). With these, every value in flight is
// bounded-finite: products <= 5.3e6*1e30 < f32 max, rcp/log args >= 1,
// exp2 args <= 0 via min3 -> no inf, no 0*inf, no NaN can form.
//
// Boundaries: BIG = (a=BIGS, s=1, U=0): s_k*exp2(m - BIGS) == 0 kills
// garbage exactly (same BIG self-propagation proof); corner = (0,1,0).
// Ring payload float4 (a, s, U); skew/ring-delay/barrier machinery is
// byte-identical to the proven R0 kernel: wave w at iter n computes diag
// k = n + 2 - 8w; lane 63 publishes to a 16-slot ring; consumer reads
// with 2-iter prefetch; write t-9 vs read-issue t-2 straddles >= 1
// barrier; 16 slots make overwrite races impossible. o flows down-lane
// by DPP; lane 0 injects o[n - 72w] from broadcast-prefetched float4s.

__device__ __forceinline__ float shr1(float x, float old) {
    return __int_as_float(__builtin_amdgcn_update_dpp(
        __float_as_int(old), __float_as_int(x), 0x138, 0xF, 0xF, false));
}

#define ITER(J, OINJ) {                                              \
    float ua = shr1(Aa, rdca);                                       \
    float us = shr1(As, rdcs);                                       \
    float uU = shr1(UU, rdcu);                                       \
    oc = shr1(oc, OINJ);                                             \
    us = fminf(fmaxf(us, 1.0f), 65536.0f);   /* s-ingress guard */   \
    rdca = rdna; rdcs = rdns; rdcu = rdnu;                           \
    float4 rr = ringr[((J) + 9) & 15];   /* for iter n+2 */          \
    rdna = rr.x; rdns = rr.y; rdnu = rr.z;                           \
    float m  = fminf(fminf(Aa, pda), ua);                            \
    float xl = __builtin_amdgcn_exp2f(m - Aa);                       \
    float xd = __builtin_amdgcn_exp2f(m - pda);                      \
    float xu = __builtin_amdgcn_exp2f(m - ua);                       \
    float el = As * xl;                                              \
    float ed = pds * xd;                                             \
    float eu = us * xu;                                              \
    float s  = el + ed + eu;                                         \
    float xo = T - oc;                                               \
    float na = fmaf(CSC * xo, xo, m);                                \
    float num = fmaf(el, UU, fmaf(ed, pdU, eu * uU));                \
    float nt  = fmaf(num, __builtin_amdgcn_rcpf(s), dr * dr);        \
    nt = fminf(nt, 1e30f);                   /* U-channel guard */   \
    if (l63) ringw[(J)] = make_float4(na, s, nt, 0.f);               \
    pda = ua; pds = us; pdU = uU;                                    \
    Aa = na; As = s; UU = nt; dr -= 1.0f;                            \
}

// Absorb the deferred log: V = Aa - log2(As) is invariant; As -> 1.
#define STRIP() {                                                    \
    Aa -= __builtin_amdgcn_logf(As);                                 \
    As = 1.0f;                                                       \
}

__global__ __launch_bounds__(256) void dilate_fused(
    const float* __restrict__ y_pred,
    const float* __restrict__ y_true,
    float* __restrict__ out)
{
    const int b   = blockIdx.x;
    const int tid = threadIdx.x;
    const int w   = tid >> 6;
    const int l   = tid & 63;
    const bool l63 = (l == 63);

    __shared__ float  o_lds[1088];   // zeros | o at [512,768) | zeros
    __shared__ float4 ring[5][16];   // [row w (4 = const BIG row for wave 0)][slot]

    const float4 z4 = make_float4(0.f, 0.f, 0.f, 0.f);
    if (tid < 128) ((float4*)o_lds)[tid] = z4;                       // [0,512)
    if (tid >= 128 && tid < 208) ((float4*)o_lds)[tid + 64] = z4;    // [768,1088)
    if (tid < 64) ((float4*)(o_lds + 512))[tid] =
        ((const float4*)(y_pred + b * NN))[tid];                     // o
    if (tid < 80) ((float4*)ring)[tid] = make_float4(BIGS, 1.f, 0.f, 0.f);

    const float T = y_true[b * NN + tid];                            // row i = tid+1
    __syncthreads();

    float Aa = BIGS, As = 1.f, UU = 0.f;
    float pda = (tid == 0) ? 0.f : BIGS;                             // V[0,0] corner
    float pds = 1.f, pdU = 0.f;
    float oc = 0.f;
    float dr = (float)(2 * tid + 8 * w);                             // (i - j) at n=0
    float rdca = BIGS, rdcs = 1.f, rdcu = 0.f;
    float rdna = BIGS, rdns = 1.f, rdnu = 0.f;

    float4* ringw = ring[w];
    const float4* ringr = ring[(w == 0) ? 4 : (w - 1)];
    const float4* o4 = ((const float4*)o_lds) + (128 - 18 * w);

    float4 fA = o4[0], fB = o4[1], fC = o4[2], fD = o4[3]; o4 += 4;

    #pragma unroll 1
    for (int blk = 0; blk < 33; ++blk) {                             // n = 0..527
        float4 gA = o4[0], gB = o4[1], gC = o4[2], gD = o4[3]; o4 += 4;
        ITER(0,  fA.x) ITER(1,  fA.y) ITER(2,  fA.z) ITER(3,  fA.w)
        __syncthreads();
        STRIP()
        ITER(4,  fB.x) ITER(5,  fB.y) ITER(6,  fB.z) ITER(7,  fB.w)
        __syncthreads();
        STRIP()
        ITER(8,  fC.x) ITER(9,  fC.y) ITER(10, fC.z) ITER(11, fC.w)
        __syncthreads();
        STRIP()
        ITER(12, fD.x) ITER(13, fD.y) ITER(14, fD.z) ITER(15, fD.w)
        __syncthreads();
        STRIP()
        fA = gA; fB = gB; fC = gC; fD = gD;
    }
    // peel n = 528..534 (wave 3 reaches k = 512 at n = 534); no barriers needed:
    // peel writes are never consumed, peel reads target slots 9..15 (disjoint
    // from peel-written slots 0..6) and data written before the last barrier.
    // Real-cell s over 7 unstripped iters stays <= ~6.6e3 (< clamp 65536).
    ITER(0, fA.x) ITER(1, fA.y) ITER(2, fA.z) ITER(3, fA.w)
    ITER(4, fB.x) ITER(5, fB.y) ITER(6, fB.z)

    if (tid == 255) {                       // wave 3, lane 63: cell (256,256)
        float V = (Aa - __builtin_amdgcn_logf(As)) * RCSC;           // a - log2 s
        float loss = 0.5f * V * (1.0f / BATCH)
                   + 0.5f * UU * (1.0f / ((float)BATCH * (float)(NN * NN)));
        atomicAdd(out, loss);
    }
}

extern "C" void kernel_launch(void* const* d_in, const int* in_sizes, int n_in,
                              void* d_out, int out_size, void* d_ws, size_t ws_size,
                              hipStream_t stream)
{
    const float* y_pred = (const float*)d_in[0];   // [64,256,1] -> o (columns)
    const float* y_true = (const float*)d_in[1];   // [64,256,1] -> t (rows)
    hipMemsetAsync(d_out, 0, sizeof(float), stream);
    dilate_fused<<<BATCH, 256, 0, stream>>>(y_pred, y_true, (float*)d_out);
}

// Round 8
// 109.353 us; speedup vs baseline: 1.0773x; 1.0335x over previous
//
#include <hip/hip_runtime.h>

#define BATCH 64
#define NN 256
// Scaled DP domain: V' = V * CSC, CSC = (1/gamma)*log2(e), gamma = 0.01.
#define CSC   144.26950408889634f
#define RCSC  0.0069314718055994531f   // 1/CSC = gamma*ln(2)
#define BIGS  1.4426950408889634e10f   // 1e8 * CSC (scaled boundary)

// R0 structure and numerics EXACTLY (proven 45.9us, absmax 0): 4 waves per
// batch, 1 DP row per lane (wave w lane l owns row i = 64w+l+1), skewed
// wavefront (wave w at iter n computes diag k = n+2-8w), eager softmin cell,
// 16-slot LDS ring, barrier every 4 iters. Three mechanical cuts:
//
// 1. WRITE-EARLY RING: value produced at iter t is written by lane 63 at the
//    TOP of iter t+1 (slot (J+15)&15). Write->read-issue gap = 6 iters, still
//    always straddles >=1 barrier (write at 4k -> read 4k+6, barrier after
//    4k+3), but the ds_write now has a full iteration to complete before the
//    barrier's lgkmcnt(0) drain -> drain ~free. First write (slot 15) stores
//    the init state (BIGS,0) = its pre-init value; peel-consumed slots 9..14
//    are all written before the final barrier (value 526 written at top of
//    n=527), peel ITER(6)'s read of slot 15 feeds n=536 (never consumed).
// 2. PER-LANE o READS: lane l's o operand at iter n is o_lds[512-72w-l+n]
//    (zero-padded layout covers [235,1048] c [0,1088)); read directly with a
//    2-iter prefetch and immediate offsets (per-block base += 16 floats).
//    Removes the oc DPP, lane-0 injection, and fA..fD float4 rotation.
//    Stride-4B across lanes -> 2 lanes/bank -> conflict-free.
// 3. SPLIT RING (ringA/ringU float arrays): 2x ds_write_b32 / ds_read_b32
//    with immediate offsets; no float2 packing movs on the VALU.
//
// Ring safety otherwise unchanged: 16 slots, consumer reads slot (J+9)&15
// (value n-7) for use at n+2; slot-reuse gap 10 iters >= 2 barriers.

__device__ __forceinline__ float shr1(float x, float old) {
    return __int_as_float(__builtin_amdgcn_update_dpp(
        __float_as_int(old), __float_as_int(x), 0x138, 0xF, 0xF, false));
}

#define ITER(J) {                                                    \
    if (l63) { ringwA[((J) + 15) & 15] = pnv;                        \
               ringwU[((J) + 15) & 15] = pnt; }                      \
    float sA = shr1(A, rdcA);                                        \
    float sU = shr1(U, rdcU);                                        \
    rdcA = rdnA; rdcU = rdnU;                                        \
    rdnA = ringrA[((J) + 9) & 15];   /* value n-7, for iter n+2 */   \
    rdnU = ringrU[((J) + 9) & 15];                                   \
    float oc = o0; o0 = o1; o1 = opb[(J)];   /* o for n+2 */         \
    float m  = fminf(fminf(A, psA), sA);                             \
    float el = __builtin_amdgcn_exp2f(m - A);                        \
    float ed = __builtin_amdgcn_exp2f(m - psA);                      \
    float eu = __builtin_amdgcn_exp2f(m - sA);                       \
    float s  = el + ed + eu;                                         \
    float x  = T - oc;                                               \
    float nv = fmaf(CSC * x, x, m - __builtin_amdgcn_logf(s));       \
    float num = fmaf(el, U, fmaf(ed, psU, eu * sU));                 \
    float nt  = fmaf(num, __builtin_amdgcn_rcpf(s), dr * dr);        \
    pnv = nv; pnt = nt;                                              \
    psA = sA; psU = sU; A = nv; U = nt; dr -= 1.0f;                  \
}

__global__ __launch_bounds__(256) void dilate_fused(
    const float* __restrict__ y_pred,
    const float* __restrict__ y_true,
    float* __restrict__ out)
{
    const int b   = blockIdx.x;
    const int tid = threadIdx.x;
    const int w   = tid >> 6;
    const int l   = tid & 63;
    const bool l63 = (l == 63);

    __shared__ float o_lds[1088];    // zeros | o at [512,768) | zeros
    __shared__ float ringA[5][16];   // [row w (4 = const BIGS row)][slot]
    __shared__ float ringU[5][16];

    const float4 z4 = make_float4(0.f, 0.f, 0.f, 0.f);
    if (tid < 128) ((float4*)o_lds)[tid] = z4;                       // [0,512)
    if (tid >= 128 && tid < 208) ((float4*)o_lds)[tid + 64] = z4;    // [768,1088)
    if (tid < 64) ((float4*)(o_lds + 512))[tid] =
        ((const float4*)(y_pred + b * NN))[tid];                     // o
    if (tid < 80) { ((float*)ringA)[tid] = BIGS; ((float*)ringU)[tid] = 0.f; }

    const float T = y_true[b * NN + tid];                            // row i = tid+1
    __syncthreads();

    float A = BIGS, U = 0.f;
    float psA = (tid == 0) ? 0.f : BIGS;                             // V[0,0] corner
    float psU = 0.f;
    float dr = (float)(2 * tid + 8 * w);                             // (i - j) at n=0
    float rdcA = BIGS, rdcU = 0.f, rdnA = BIGS, rdnU = 0.f;
    float pnv = BIGS, pnt = 0.f;                                     // write-early regs

    float* ringwA = ringA[w];
    float* ringwU = ringU[w];
    const float* ringrA = ringA[(w == 0) ? 4 : (w - 1)];
    const float* ringrU = ringU[(w == 0) ? 4 : (w - 1)];

    // per-lane o: element 512 - 72w - l + n; prefetch depth 2.
    const float* opb = o_lds + (512 - 72 * w - l);
    float o0 = opb[0], o1 = opb[1];
    opb += 2;                        // opb[J] at block B reads n = 16B + J + 2

    #pragma unroll 1
    for (int blk = 0; blk < 33; ++blk) {                             // n = 0..527
        ITER(0)  ITER(1)  ITER(2)  ITER(3)
        __syncthreads();
        ITER(4)  ITER(5)  ITER(6)  ITER(7)
        __syncthreads();
        ITER(8)  ITER(9)  ITER(10) ITER(11)
        __syncthreads();
        ITER(12) ITER(13) ITER(14) ITER(15)
        __syncthreads();
        opb += 16;
    }
    // peel n = 528..534 (wave 3 reaches k = 512 at n = 534); no barriers needed:
    // peel-consumed ring data (slots 9..14) was written before the last barrier;
    // peel writes (slots 15,0..5) are never consumed; slot-15 read at peel J=6
    // feeds n=536 (discarded).
    ITER(0) ITER(1) ITER(2) ITER(3)
    ITER(4) ITER(5) ITER(6)

    if (tid == 255) {                       // wave 3, lane 63: cell (256,256)
        float loss = 0.5f * (A * RCSC) * (1.0f / BATCH)
                   + 0.5f * U * (1.0f / ((float)BATCH * (float)(NN * NN)));
        atomicAdd(out, loss);
    }
}

extern "C" void kernel_launch(void* const* d_in, const int* in_sizes, int n_in,
                              void* d_out, int out_size, void* d_ws, size_t ws_size,
                              hipStream_t stream)
{
    const float* y_pred = (const float*)d_in[0];   // [64,256,1] -> o (columns)
    const float* y_true = (const float*)d_in[1];   // [64,256,1] -> t (rows)
    hipMemsetAsync(d_out, 0, sizeof(float), stream);
    dilate_fused<<<BATCH, 256, 0, stream>>>(y_pred, y_true, (float*)d_out);
}

// Round 9
// 99.994 us; speedup vs baseline: 1.1781x; 1.0936x over previous
//
#include <hip/hip_runtime.h>

#define BATCH 64
#define NN 256
// Scaled DP domain: V' = V * CSC, CSC = (1/gamma)*log2(e), gamma = 0.01.
#define CSC   144.26950408889634f
#define RCSC  0.0069314718055994531f   // 1/CSC = gamma*ln(2)
#define SQC   12.011224079f            // sqrt(CSC): T,o pre-scaled so x*x = CSC*(T-o)^2
#define BIGS  1.4426950408889634e10f   // 1e8 * CSC (scaled boundary)

// R0 structure and numerics EXACTLY (proven 45.9us): 4 waves per batch, 1 DP
// row per lane (wave w lane l owns row 64w+l+1), skewed wavefront (wave w at
// iter n computes diag k = n+2-8w), eager softmin cell, float2 16-slot ring,
// o flowing down-lane by DPP with lane-0 injection from float4 prefetch,
// barrier every 4 iters. Changes vs R0 (op count: -1 mul; LDS ops same count,
// repositioned so the barrier's lgkmcnt(0) drain finds them already complete):
//
// 1. WRITE-EARLY RING (float2): value produced at iter t is written by lane 63
//    at the TOP of iter t+1 (slot t&15 = (J+15)&15) from pending regs pnv/pnt.
//    The write's data is ready at iter start -> it completes during the iter,
//    so the pre-barrier drain no longer waits ~100 cyc on a write that depended
//    on the end of the cell chain. First write = (BIGS,0) = slot 15's pre-init.
// 2. FRONT-LOADED RING READS: the 4 slot-reads of each phase issue only at
//    J=0,1 (2x float2 each), into pipeline regs v0..v3 with static schedule
//    uses: J0:v2 J1:v3 J2:v0 J3:v1 (period 4); reads: J=0 -> v0,v1 = slots
//    (J+9,J+10)&15; J=1 -> v2,v3 = slots (J+10,J+11)&15 (issued AFTER the
//    core so J=1's use of old v3 precedes the overwrite). Use-age stays 9
//    (value n-9 consumed at iter n) -> skew 8/wave and 535 iters unchanged.
//    Every write (top of v+1) -> read (at v+7) straddles >=1 barrier
//    (verified for all 8 read positions); slot reuse gap 10 iters >= 2
//    barriers; barrier caps producer/consumer drift < 4 iters.
//    No read issues in the last 2 iters of a phase -> drain ~free.
// 3. sqrt(CSC) PRE-SCALE of T and o at load: x = Ts - os, nv = fma(x,x,...)
//    saves the CSC*x mul every iter.
//
// Peel (n=528..534): reads RD0(0),RD1(1),RD0(4) target slots 9..14, all
// written before the final barrier; RD1(5) is dead (feeds n>=536) and skipped.
// Peel writes (slots 15,0..5) are never consumed. BIG self-propagation
// unchanged: garbage cells keep m=BIGS, x^2 (<~5e3) vanishes in ulp(BIGS).

__device__ __forceinline__ float shr1(float x, float old) {
    return __int_as_float(__builtin_amdgcn_update_dpp(
        __float_as_int(old), __float_as_int(x), 0x138, 0xF, 0xF, false));
}

#define ITER(J, OINJ, PV) {                                          \
    if (l63) ringw[((J) + 15) & 15] = make_float2(pnv, pnt);         \
    float sA = shr1(A, (PV).x);                                      \
    float sU = shr1(U, (PV).y);                                      \
    oc = shr1(oc, OINJ);                                             \
    float m  = fminf(fminf(A, psA), sA);                             \
    float el = __builtin_amdgcn_exp2f(m - A);                        \
    float ed = __builtin_amdgcn_exp2f(m - psA);                      \
    float eu = __builtin_amdgcn_exp2f(m - sA);                       \
    float s  = el + ed + eu;                                         \
    float x  = T - oc;                                               \
    float nv = fmaf(x, x, m - __builtin_amdgcn_logf(s));             \
    float num = fmaf(el, U, fmaf(ed, psU, eu * sU));                 \
    float nt  = fmaf(num, __builtin_amdgcn_rcpf(s), dr * dr);        \
    pnv = nv; pnt = nt;                                              \
    psA = sA; psU = sU; A = nv; U = nt; dr -= 1.0f;                  \
}

#define RD0(J) { v0 = ringr[((J) + 9) & 15]; v1 = ringr[((J) + 10) & 15]; }
#define RD1(J) { v2 = ringr[((J) + 10) & 15]; v3 = ringr[((J) + 11) & 15]; }

__global__ __launch_bounds__(256) void dilate_fused(
    const float* __restrict__ y_pred,
    const float* __restrict__ y_true,
    float* __restrict__ out)
{
    const int b   = blockIdx.x;
    const int tid = threadIdx.x;
    const int w   = tid >> 6;
    const int l   = tid & 63;
    const bool l63 = (l == 63);

    __shared__ float  o_lds[1088];   // zeros | sqrt(CSC)*o at [512,768) | zeros
    __shared__ float2 ring[5][16];   // [row w (4 = const BIGS row for wave 0)][slot]

    const float4 z4 = make_float4(0.f, 0.f, 0.f, 0.f);
    if (tid < 128) ((float4*)o_lds)[tid] = z4;                       // [0,512)
    if (tid >= 128 && tid < 208) ((float4*)o_lds)[tid + 64] = z4;    // [768,1088)
    if (tid < 64) {
        float4 ov = ((const float4*)(y_pred + b * NN))[tid];
        ov.x *= SQC; ov.y *= SQC; ov.z *= SQC; ov.w *= SQC;
        ((float4*)(o_lds + 512))[tid] = ov;                          // scaled o
    }
    if (tid < 80) ((float2*)ring)[tid] = make_float2(BIGS, 0.f);     // all slots

    const float T = y_true[b * NN + tid] * SQC;                      // row i = tid+1
    __syncthreads();

    float A = BIGS, U = 0.f;
    float psA = (tid == 0) ? 0.f : BIGS;                             // V[0,0] corner
    float psU = 0.f;
    float oc = 0.f;
    float dr = (float)(2 * tid + 8 * w);                             // (i - j) at n=0
    float pnv = BIGS, pnt = 0.f;                                     // write-early regs
    float2 v0 = make_float2(BIGS, 0.f), v1 = v0, v2 = v0, v3 = v0;   // read pipeline

    float2* ringw = ring[w];
    const float2* ringr = ring[(w == 0) ? 4 : (w - 1)];
    const float4* o4 = ((const float4*)o_lds) + (128 - 18 * w);

    float4 fA = o4[0], fB = o4[1], fC = o4[2], fD = o4[3]; o4 += 4;

    #pragma unroll 1
    for (int blk = 0; blk < 33; ++blk) {                             // n = 0..527
        float4 gA = o4[0], gB = o4[1], gC = o4[2], gD = o4[3]; o4 += 4;
        ITER(0,  fA.x, v2) RD0(0)
        ITER(1,  fA.y, v3) RD1(1)
        ITER(2,  fA.z, v0)
        ITER(3,  fA.w, v1)
        __syncthreads();
        ITER(4,  fB.x, v2) RD0(4)
        ITER(5,  fB.y, v3) RD1(5)
        ITER(6,  fB.z, v0)
        ITER(7,  fB.w, v1)
        __syncthreads();
        ITER(8,  fC.x, v2) RD0(8)
        ITER(9,  fC.y, v3) RD1(9)
        ITER(10, fC.z, v0)
        ITER(11, fC.w, v1)
        __syncthreads();
        ITER(12, fD.x, v2) RD0(12)
        ITER(13, fD.y, v3) RD1(13)
        ITER(14, fD.z, v0)
        ITER(15, fD.w, v1)
        __syncthreads();
        fA = gA; fB = gB; fC = gC; fD = gD;
    }
    // peel n = 528..534 (wave 3 reaches k = 512 at n = 534); no barriers:
    // consumed reads (slots 9..14) were written before the last barrier;
    // peel writes (slots 15,0..5) are never consumed; RD1(5) is dead -> skip.
    ITER(0, fA.x, v2) RD0(0)
    ITER(1, fA.y, v3) RD1(1)
    ITER(2, fA.z, v0)
    ITER(3, fA.w, v1)
    ITER(4, fB.x, v2) RD0(4)
    ITER(5, fB.y, v3)
    ITER(6, fB.z, v0)

    if (tid == 255) {                       // wave 3, lane 63: cell (256,256)
        float loss = 0.5f * (A * RCSC) * (1.0f / BATCH)
                   + 0.5f * U * (1.0f / ((float)BATCH * (float)(NN * NN)));
        atomicAdd(out, loss);
    }
}

extern "C" void kernel_launch(void* const* d_in, const int* in_sizes, int n_in,
                              void* d_out, int out_size, void* d_ws, size_t ws_size,
                              hipStream_t stream)
{
    const float* y_pred = (const float*)d_in[0];   // [64,256,1] -> o (columns)
    const float* y_true = (const float*)d_in[1];   // [64,256,1] -> t (rows)
    hipMemsetAsync(d_out, 0, sizeof(float), stream);
    dilate_fused<<<BATCH, 256, 0, stream>>>(y_pred, y_true, (float*)d_out);
}

// Round 10
// 97.054 us; speedup vs baseline: 1.2138x; 1.0303x over previous
//
#include <hip/hip_runtime.h>

#define BATCH 64
#define NN 256
// Scaled DP domain: V' = V * CSC, CSC = (1/gamma)*log2(e), gamma = 0.01.
#define CSC   144.26950408889634f
#define RCSC  0.0069314718055994531f   // 1/CSC = gamma*ln(2)
#define BIGS  1.4426950408889634e10f   // 1e8 * CSC (scaled boundary)

// R0 cell math EXACTLY (proven 45.9us, absmax 0); barrier cadence halved:
// barrier every 8 iters (68 barriers vs 134). Ring-safety algebra forces
// skew S=12 (u=13): wave w at iter n computes diag k = n+2-12w; 547 iters.
// o-prefetch base (64+S)w = 76w floats stays float4-aligned (76%4==0).
//
// Ring schedule (16 slots, value v lives in slot v&15, written at END of
// iter v by lane 63): consumer reads value v at its iter v+8 into an
// 8-register static pipeline q0..q7 (period 8 divides the 16-unroll), and
// consumes it at iter v+13 as the DPP old-operand. Proven for ALL v:
//   write(v) -> read(v+8): 8 apart -> always straddles one barrier
//     (barriers after n%8==7; windows [8k,8k+7]; v and v+8 in different
//     windows; lockstep at barriers bounds intra-window drift).
//   read(v+8) -> slot rewrite(v+16): 8 apart -> always barrier-separated.
//   Same-window slot-disjointness: producer window-writes touch slots
//     {8k..8k+7}&15, consumer window-reads touch {8k+8..8k+15}&15 - disjoint.
// Static reg map (16-unroll, n=16B+J): ITER(J) uses q[(J+3)&7] (= value
// n-13); RD(J) fills q[J&7] from slot (J+8)&15 (= value n-8). RD(7)/RD(15)
// issue one iter early so no fresh ds_read sits in the barrier drain.
// Reads q init = (BIGS,0) and slots 8..15 pre-init cover uses n<13 exactly.
//
// Peel n=544..546 (wave 3 reaches cell (256,256) at n=546): uses q3,q4,q5
// (read at n=539..541, values 531..533, written in windows before the last
// barrier after n=543); peel writes (slots 0..2) are never consumed.
// Everything else (DPP row handoff, o down-lane flow with lane-0 injection
// from broadcast float4 prefetch, BIG self-propagation killing all skew
// wedge cells exactly, corner via psA init) is byte-identical to R0.

__device__ __forceinline__ float shr1(float x, float old) {
    return __int_as_float(__builtin_amdgcn_update_dpp(
        __float_as_int(old), __float_as_int(x), 0x138, 0xF, 0xF, false));
}

#define ITER(J, OINJ, QV) {                                          \
    float sA = shr1(A, (QV).x);                                      \
    float sU = shr1(U, (QV).y);                                      \
    oc = shr1(oc, OINJ);                                             \
    float m  = fminf(fminf(A, psA), sA);                             \
    float el = __builtin_amdgcn_exp2f(m - A);                        \
    float ed = __builtin_amdgcn_exp2f(m - psA);                      \
    float eu = __builtin_amdgcn_exp2f(m - sA);                       \
    float s  = el + ed + eu;                                         \
    float x  = T - oc;                                               \
    float nv = fmaf(CSC * x, x, m - __builtin_amdgcn_logf(s));       \
    float num = fmaf(el, U, fmaf(ed, psU, eu * sU));                 \
    float nt  = fmaf(num, __builtin_amdgcn_rcpf(s), dr * dr);        \
    if (l63) ringw[(J)] = make_float2(nv, nt);                       \
    psA = sA; psU = sU; A = nv; U = nt; dr -= 1.0f;                  \
}

#define RD(J, QD) { QD = ringr[((J) + 8) & 15]; }

__global__ __launch_bounds__(256) void dilate_fused(
    const float* __restrict__ y_pred,
    const float* __restrict__ y_true,
    float* __restrict__ out)
{
    const int b   = blockIdx.x;
    const int tid = threadIdx.x;
    const int w   = tid >> 6;
    const int l   = tid & 63;
    const bool l63 = (l == 63);

    __shared__ float  o_lds[1088];   // zeros | o at [512,768) | zeros
    __shared__ float2 ring[5][16];   // [row w (4 = const BIGS row for wave 0)][slot]

    const float4 z4 = make_float4(0.f, 0.f, 0.f, 0.f);
    if (tid < 128) ((float4*)o_lds)[tid] = z4;                       // [0,512)
    if (tid >= 128 && tid < 208) ((float4*)o_lds)[tid + 64] = z4;    // [768,1088)
    if (tid < 64) ((float4*)(o_lds + 512))[tid] =
        ((const float4*)(y_pred + b * NN))[tid];                     // o
    if (tid < 80) ((float2*)ring)[tid] = make_float2(BIGS, 0.f);     // all slots

    const float T = y_true[b * NN + tid];                            // row i = tid+1
    __syncthreads();

    float A = BIGS, U = 0.f;
    float psA = (tid == 0) ? 0.f : BIGS;                             // V[0,0] corner
    float psU = 0.f;
    float oc = 0.f;
    float dr = (float)(2 * tid + 12 * w);                            // (i - j) at n=0
    const float2 qi = make_float2(BIGS, 0.f);
    float2 q0 = qi, q1 = qi, q2 = qi, q3 = qi, q4 = qi, q5 = qi, q6 = qi, q7 = qi;

    float2* ringw = ring[w];
    const float2* ringr = ring[(w == 0) ? 4 : (w - 1)];
    const float4* o4 = ((const float4*)o_lds) + (128 - 19 * w);      // 76w floats

    float4 fA = o4[0], fB = o4[1], fC = o4[2], fD = o4[3]; o4 += 4;

    #pragma unroll 1
    for (int blk = 0; blk < 34; ++blk) {                             // n = 0..543
        float4 gA = o4[0], gB = o4[1], gC = o4[2], gD = o4[3]; o4 += 4;
        ITER(0,  fA.x, q3) RD(0,  q0)
        ITER(1,  fA.y, q4) RD(1,  q1)
        ITER(2,  fA.z, q5) RD(2,  q2)
        ITER(3,  fA.w, q6) RD(3,  q3)
        ITER(4,  fB.x, q7) RD(4,  q4)
        ITER(5,  fB.y, q0) RD(5,  q5)
        ITER(6,  fB.z, q1) RD(6,  q6) RD(7, q7)
        ITER(7,  fB.w, q2)
        __syncthreads();
        ITER(8,  fC.x, q3) RD(8,  q0)
        ITER(9,  fC.y, q4) RD(9,  q1)
        ITER(10, fC.z, q5) RD(10, q2)
        ITER(11, fC.w, q6) RD(11, q3)
        ITER(12, fD.x, q7) RD(12, q4)
        ITER(13, fD.y, q0) RD(13, q5)
        ITER(14, fD.z, q1) RD(14, q6) RD(15, q7)
        ITER(15, fD.w, q2)
        __syncthreads();
        fA = gA; fB = gB; fC = gC; fD = gD;
    }
    // peel n = 544..546 (wave 3 reaches k = 512 at n = 546); no barriers:
    // consumed q3,q4,q5 were read at n=539..541 from values 531..533 (written
    // >= 1 barrier earlier); peel writes (slots 0..2) are never consumed.
    ITER(0, fA.x, q3)
    ITER(1, fA.y, q4)
    ITER(2, fA.z, q5)

    if (tid == 255) {                       // wave 3, lane 63: cell (256,256)
        float loss = 0.5f * (A * RCSC) * (1.0f / BATCH)
                   + 0.5f * U * (1.0f / ((float)BATCH * (float)(NN * NN)));
        atomicAdd(out, loss);
    }
}

extern "C" void kernel_launch(void* const* d_in, const int* in_sizes, int n_in,
                              void* d_out, int out_size, void* d_ws, size_t ws_size,
                              hipStream_t stream)
{
    const float* y_pred = (const float*)d_in[0];   // [64,256,1] -> o (columns)
    const float* y_true = (const float*)d_in[1];   // [64,256,1] -> t (rows)
    hipMemsetAsync(d_out, 0, sizeof(float), stream);
    dilate_fused<<<BATCH, 256, 0, stream>>>(y_pred, y_true, (float*)d_out);
}

// Round 11
// 94.642 us; speedup vs baseline: 1.2447x; 1.0255x over previous
//
#include <hip/hip_runtime.h>

#define BATCH 64
#define NN 256
// Scaled DP domain: V' = V * CSC, CSC = (1/gamma)*log2(e), gamma = 0.01.
#define CSC   144.26950408889634f
#define RCSC  0.0069314718055994531f   // 1/CSC = gamma*ln(2)
#define SQC   12.011224079f            // sqrt(CSC): T,o pre-scaled so x*x = CSC*(T-o)^2
#define BIGS  1.4426950408889634e10f   // 1e8 * CSC (scaled boundary)

// R10 structure (4 waves/batch, 1 row/lane, skew S=12, 547 iters, barrier
// every 8 iters, u=13) with four op-count cuts, numerics unchanged:
//  1. v_min3_f32 inline asm for m (2 fmin -> 1 op, shorter chain).
//  2. sqrt(CSC) pre-scale of T,o (kills CSC*x mul; R9-proven absmax 0).
//  3. 32-iter double body (f-bank I=0..15, g-bank I=16..31; loads write the
//     opposite bank) -> no fA=gA rotation movs.
//  4. PAIRED RING (float4 = nv,nt of values 2m,2m+1): write once per 2 iters
//     (odd n, slot m&7, static immediate), read once per 2 iters (even n,
//     pair m=(n-8)/2, slot m&7, q[m&3] of 4 float4 pipeline regs, period-8
//     static rotation). Consumption at iter n' uses value n'-13: pair
//     floor((n'-13)/2), element zw if n' even (v odd) else xy.
//     Safety (all proven for every v): write(pair m)@2m+1 -> read@2m+8: the
//     interval contains 4 consecutive evens -> always crosses a barrier
//     (barriers after n%8==7); slot reuse @2m+17 vs read @2m+8: gap 9 ->
//     barrier-separated; q reg loaded at I, consumed I+5/I+6, reloaded I+8.
// Peel n=544..546: consumes values 531..533 (pairs 265/266 read at n=538/540,
// written at 531/533, >=1 barrier before loop end); peel writes skipped
// (never consumed). o: per-wave base 512-76w, zero-padded [0,512)+[768,1088)
// covers all wedge columns; BIG self-propagation kills wedge cells exactly.

__device__ __forceinline__ float shr1(float x, float old) {
    return __int_as_float(__builtin_amdgcn_update_dpp(
        __float_as_int(old), __float_as_int(x), 0x138, 0xF, 0xF, false));
}

__device__ __forceinline__ float min3f(float a, float b, float c) {
    float d;
    asm("v_min3_f32 %0, %1, %2, %3" : "=v"(d) : "v"(a), "v"(b), "v"(c));
    return d;
}

#define CELLX(OINJ, QA, QB, PRE, POST) {                             \
    float sA = shr1(A, QA);                                          \
    float sU = shr1(U, QB);                                          \
    oc = shr1(oc, OINJ);                                             \
    PRE                                                              \
    float m  = min3f(A, psA, sA);                                    \
    float el = __builtin_amdgcn_exp2f(m - A);                        \
    float ed = __builtin_amdgcn_exp2f(m - psA);                      \
    float eu = __builtin_amdgcn_exp2f(m - sA);                       \
    float s  = el + ed + eu;                                         \
    float x  = T - oc;                                               \
    float nv = fmaf(x, x, m - __builtin_amdgcn_logf(s));             \
    float num = fmaf(el, U, fmaf(ed, psU, eu * sU));                 \
    float nt  = fmaf(num, __builtin_amdgcn_rcpf(s), dr * dr);        \
    POST                                                             \
    psA = sA; psU = sU; A = nv; U = nt; dr -= 1.0f;                  \
}

#define CELL(OINJ, QA, QB) CELLX(OINJ, QA, QB, , )
#define CELL_W(OINJ, QA, QB, SLOT)                                   \
    CELLX(OINJ, QA, QB, float wv = A; float wu = U;,                 \
          if (l63) ringw[SLOT] = make_float4(wv, wu, nv, nt);)

__global__ __launch_bounds__(256) void dilate_fused(
    const float* __restrict__ y_pred,
    const float* __restrict__ y_true,
    float* __restrict__ out)
{
    const int b   = blockIdx.x;
    const int tid = threadIdx.x;
    const int w   = tid >> 6;
    const int l   = tid & 63;
    const bool l63 = (l == 63);

    __shared__ float  o_lds[1088];   // zeros | sqrt(CSC)*o at [512,768) | zeros
    __shared__ float4 ring[5][8];    // [row w (4 = const BIGS row)][pair slot]

    const float4 z4 = make_float4(0.f, 0.f, 0.f, 0.f);
    if (tid < 128) ((float4*)o_lds)[tid] = z4;                       // [0,512)
    if (tid >= 128 && tid < 208) ((float4*)o_lds)[tid + 64] = z4;    // [768,1088)
    if (tid < 64) {
        float4 ov = ((const float4*)(y_pred + b * NN))[tid];
        ov.x *= SQC; ov.y *= SQC; ov.z *= SQC; ov.w *= SQC;
        ((float4*)(o_lds + 512))[tid] = ov;                          // scaled o
    }
    if (tid < 40) ((float4*)ring)[tid] = make_float4(BIGS, 0.f, BIGS, 0.f);

    const float T = y_true[b * NN + tid] * SQC;                      // row i = tid+1
    __syncthreads();

    float A = BIGS, U = 0.f;
    float psA = (tid == 0) ? 0.f : BIGS;                             // V[0,0] corner
    float psU = 0.f;
    float oc = 0.f;
    float dr = (float)(2 * tid + 12 * w);                            // (i - j) at n=0
    const float4 qi = make_float4(BIGS, 0.f, BIGS, 0.f);
    float4 q0 = qi, q1 = qi, q2 = qi, q3 = qi;

    float4* ringw = ring[w];
    const float4* ringr = ring[(w == 0) ? 4 : (w - 1)];
    const float4* o4 = ((const float4*)o_lds) + (128 - 19 * w);      // 76w floats

    float4 fA = o4[0], fB = o4[1], fC = o4[2], fD = o4[3]; o4 += 4;
    float4 gA, gB, gC, gD;

    #pragma unroll 1
    for (int blk = 0; blk < 17; ++blk) {                             // n = 0..543
        gA = o4[0]; gB = o4[1]; gC = o4[2]; gD = o4[3];
        q0 = ringr[4]; CELL  (fA.x, q1.z, q1.w)
                       CELL_W(fA.y, q2.x, q2.y, 0)
        q1 = ringr[5]; CELL  (fA.z, q2.z, q2.w)
                       CELL_W(fA.w, q3.x, q3.y, 1)
        q2 = ringr[6]; CELL  (fB.x, q3.z, q3.w)
                       CELL_W(fB.y, q0.x, q0.y, 2)
        q3 = ringr[7]; CELL  (fB.z, q0.z, q0.w)
                       CELL_W(fB.w, q1.x, q1.y, 3)
        __syncthreads();
        q0 = ringr[0]; CELL  (fC.x, q1.z, q1.w)
                       CELL_W(fC.y, q2.x, q2.y, 4)
        q1 = ringr[1]; CELL  (fC.z, q2.z, q2.w)
                       CELL_W(fC.w, q3.x, q3.y, 5)
        q2 = ringr[2]; CELL  (fD.x, q3.z, q3.w)
                       CELL_W(fD.y, q0.x, q0.y, 6)
        q3 = ringr[3]; CELL  (fD.z, q0.z, q0.w)
                       CELL_W(fD.w, q1.x, q1.y, 7)
        __syncthreads();
        fA = o4[4]; fB = o4[5]; fC = o4[6]; fD = o4[7]; o4 += 8;
        q0 = ringr[4]; CELL  (gA.x, q1.z, q1.w)
                       CELL_W(gA.y, q2.x, q2.y, 0)
        q1 = ringr[5]; CELL  (gA.z, q2.z, q2.w)
                       CELL_W(gA.w, q3.x, q3.y, 1)
        q2 = ringr[6]; CELL  (gB.x, q3.z, q3.w)
                       CELL_W(gB.y, q0.x, q0.y, 2)
        q3 = ringr[7]; CELL  (gB.z, q0.z, q0.w)
                       CELL_W(gB.w, q1.x, q1.y, 3)
        __syncthreads();
        q0 = ringr[0]; CELL  (gC.x, q1.z, q1.w)
                       CELL_W(gC.y, q2.x, q2.y, 4)
        q1 = ringr[1]; CELL  (gC.z, q2.z, q2.w)
                       CELL_W(gC.w, q3.x, q3.y, 5)
        q2 = ringr[2]; CELL  (gD.x, q3.z, q3.w)
                       CELL_W(gD.y, q0.x, q0.y, 6)
        q3 = ringr[3]; CELL  (gD.z, q0.z, q0.w)
                       CELL_W(gD.w, q1.x, q1.y, 7)
        __syncthreads();
    }
    // peel n = 544..546 (wave 3 reaches cell (256,256) at n = 546):
    // q-elements follow the period-8 pattern (I'%8 = 0,1,2); no ring ops.
    CELL(fA.x, q1.z, q1.w)
    CELL(fA.y, q2.x, q2.y)
    CELL(fA.z, q2.z, q2.w)

    if (tid == 255) {                       // wave 3, lane 63: cell (256,256)
        float loss = 0.5f * (A * RCSC) * (1.0f / BATCH)
                   + 0.5f * U * (1.0f / ((float)BATCH * (float)(NN * NN)));
        atomicAdd(out, loss);
    }
}

extern "C" void kernel_launch(void* const* d_in, const int* in_sizes, int n_in,
                              void* d_out, int out_size, void* d_ws, size_t ws_size,
                              hipStream_t stream)
{
    const float* y_pred = (const float*)d_in[0];   // [64,256,1] -> o (columns)
    const float* y_true = (const float*)d_in[1];   // [64,256,1] -> t (rows)
    hipMemsetAsync(d_out, 0, sizeof(float), stream);
    dilate_fused<<<BATCH, 256, 0, stream>>>(y_pred, y_true, (float*)d_out);
}